// Round 8
// baseline (691.420 us; speedup 1.0000x reference)
//
#include <hip/hip_runtime.h>
#include <hip/hip_bf16.h>

#define Nn 16384
#define Dd 256
#define L2E 1.4426950408889634f
#define LN2 0.6931471805599453f

typedef __attribute__((ext_vector_type(8))) int int8v;
typedef __attribute__((ext_vector_type(16))) float f32x16;

__device__ inline void gload_lds16(const void* g, void* l) {
    __builtin_amdgcn_global_load_lds(
        (const __attribute__((address_space(1))) void*)g,
        (__attribute__((address_space(3))) void*)l, 16, 0, 0);
}

// fp32 -> fp8 e4m3 (HW RNE). A pre-scaled by log2e: epilogue softplus works in
// exp2/log2 domain with no per-element muls.
__global__ __launch_bounds__(256) void cvt_kernel(
        const float4* __restrict__ a, const float4* __restrict__ b,
        int2* __restrict__ oa, int2* __restrict__ ob) {
    int i = blockIdx.x * 256 + threadIdx.x;
    float4 a0 = a[2 * i], a1 = a[2 * i + 1];
    float4 b0 = b[2 * i], b1 = b[2 * i + 1];
    int alo = __builtin_amdgcn_cvt_pk_fp8_f32(a0.x * L2E, a0.y * L2E, 0, false);
    alo     = __builtin_amdgcn_cvt_pk_fp8_f32(a0.z * L2E, a0.w * L2E, alo, true);
    int ahi = __builtin_amdgcn_cvt_pk_fp8_f32(a1.x * L2E, a1.y * L2E, 0, false);
    ahi     = __builtin_amdgcn_cvt_pk_fp8_f32(a1.z * L2E, a1.w * L2E, ahi, true);
    int blo = __builtin_amdgcn_cvt_pk_fp8_f32(b0.x, b0.y, 0, false);
    blo     = __builtin_amdgcn_cvt_pk_fp8_f32(b0.z, b0.w, blo, true);
    int bhi = __builtin_amdgcn_cvt_pk_fp8_f32(b1.x, b1.y, 0, false);
    bhi     = __builtin_amdgcn_cvt_pk_fp8_f32(b1.z, b1.w, bhi, true);
    oa[i] = make_int2(alo, ahi);
    ob[i] = make_int2(blo, bhi);
}

// 2x ds_read_b128 of one lane's 32 contiguous K-bytes from a [rows][256B]
// full-K LDS tile, XOR-deswizzled (16 chunks/row, chunk ^= row&15).
__device__ inline int8v read_frag256(const unsigned char* base, int rr, int cb) {
    int x = rr & 15;
    int4 lo = *(const int4*)&base[rr * 256 + ((cb ^ x) * 16)];
    int4 hi = *(const int4*)&base[rr * 256 + (((cb + 1) ^ x) * 16)];
    int8v r;
    r[0] = lo.x; r[1] = lo.y; r[2] = lo.z; r[3] = lo.w;
    r[4] = hi.x; r[5] = hi.y; r[6] = hi.z; r[7] = hi.w;
    return r;
}

// Fused MX-fp8 GEMM (sim' = log2e * za.zb^T, unit e8m0 scales) + siglip loss.
// Persistent-A pipelined-B: block = 256 M-rows x 1024 N-cols (8 tiles of 128).
// A[256][256B] staged once (64KB LDS) -> A-frags hoisted to 64 VGPRs.
// B double-buffered [2][128][256B] (64KB), 2-tiles-ahead prefetch, counted
// vmcnt(4) only (no vmcnt(0) in loop). Per-tile loss epilogue placed between
// stage-issue and the wait so it hides HBM latency. 512 thr = 8 waves (4Mx2N),
// wave tile 64x64 -> acc[2][2] f32x16. ~180 VGPR < 256 cap at (512,2).
__global__ __launch_bounds__(512, 2) void siglip_kernel(
        const unsigned char* __restrict__ ga,   // za*log2e fp8 [16384][256]
        const unsigned char* __restrict__ gb,   // zb fp8 [16384][256]
        const float* __restrict__ bp,           // bias scalar
        float* __restrict__ out) {
    __shared__ unsigned char As[256 * 256];      // 64 KB
    __shared__ unsigned char Bs[2][128 * 256];   // 64 KB
    __shared__ float wsum[8];

    const int tid  = threadIdx.x;
    const int lane = tid & 63;
    const int wid  = tid >> 6;
    const int wm   = wid >> 1;     // 0..3 -> 64-row slice of the 256-row tile
    const int wn   = wid & 1;      // 0..1 -> 64-col slice of the 128-col tile
    const int l31  = lane & 31;
    const int h    = lane >> 5;

    // XCD-chunked bijective swizzle (grid 1024 = 8 XCD x 128); consecutive
    // nid share the A panel (same by) and sweep B -> L2 locality per XCD.
    const int bid = blockIdx.x;
    const int nid = (bid & 7) * 128 + (bid >> 3);
    const int by  = nid >> 4;      // 0..63  M-tile (256 rows)
    const int bxs = nid & 15;      // 0..15  N-supertile (1024 cols)
    const size_t rowA0 = (size_t)by * 256;
    const int    rB0   = bxs * 1024;

    const float b2 = bp[0] * L2E;

    // ---- stage A once: 4096 chunks, 8/thread; source chunk pre-swizzled
    // ((c&15)^(row&15)) so read_frag256's XOR'd reads deswizzle correctly ----
#pragma unroll
    for (int p = 0; p < 8; ++p) {
        int c = p * 512 + tid; int row = c >> 4;
        int scl = (c & 15) ^ (row & 15);
        gload_lds16(&ga[(rowA0 + row) * Dd + scl * 16], &As[c * 16]);
    }

#define STAGE_B(BUF, T)                                                       \
    {                                                                         \
        _Pragma("unroll")                                                     \
        for (int p = 0; p < 4; ++p) {                                         \
            int c = p * 512 + tid; int row = c >> 4;                          \
            int scl = (c & 15) ^ (row & 15);                                  \
            gload_lds16(&gb[(size_t)(rB0 + (T) * 128 + row) * Dd + scl * 16], \
                        &Bs[BUF][c * 16]);                                    \
        }                                                                     \
    }

    STAGE_B(0, 0)
    STAGE_B(1, 1)

    asm volatile("s_waitcnt vmcnt(8)" ::: "memory");   // A landed (B0+B1 out)
    __builtin_amdgcn_s_barrier();
    asm volatile("" ::: "memory");

    // hoist all A fragments to registers (read A from LDS exactly once)
    int8v aF[4][2];
#pragma unroll
    for (int s = 0; s < 4; ++s)
#pragma unroll
        for (int mf = 0; mf < 2; ++mf)
            aF[s][mf] = read_frag256(As, wm * 64 + mf * 32 + l31, s * 4 + h * 2);

    asm volatile("s_waitcnt vmcnt(4)" ::: "memory");   // B0 landed
    __builtin_amdgcn_s_barrier();
    asm volatile("" ::: "memory");

    float r1 = 0.f, r2 = 0.f, r2b = 0.f, ld = 0.f;
    const int diagblk = (bxs == (by >> 2));
    const int dtile   = (by & 3);

#pragma unroll 2
    for (int t = 0; t < 8; ++t) {
        const unsigned char* Bb = Bs[t & 1];

        f32x16 acc[2][2];
#pragma unroll
        for (int mf = 0; mf < 2; ++mf)
#pragma unroll
            for (int nf = 0; nf < 2; ++nf)
#pragma unroll
                for (int q = 0; q < 16; ++q) acc[mf][nf][q] = -b2;

#pragma unroll
        for (int s = 0; s < 4; ++s) {
            int cb = s * 4 + h * 2;
            int8v bF0 = read_frag256(Bb, wn * 64 + l31, cb);
            int8v bF1 = read_frag256(Bb, wn * 64 + 32 + l31, cb);
            acc[0][0] = __builtin_amdgcn_mfma_scale_f32_32x32x64_f8f6f4(
                aF[s][0], bF0, acc[0][0], 0, 0, 0, 0x7F7F7F7F, 0, 0x7F7F7F7F);
            acc[0][1] = __builtin_amdgcn_mfma_scale_f32_32x32x64_f8f6f4(
                aF[s][0], bF1, acc[0][1], 0, 0, 0, 0x7F7F7F7F, 0, 0x7F7F7F7F);
            acc[1][0] = __builtin_amdgcn_mfma_scale_f32_32x32x64_f8f6f4(
                aF[s][1], bF0, acc[1][0], 0, 0, 0, 0x7F7F7F7F, 0, 0x7F7F7F7F);
            acc[1][1] = __builtin_amdgcn_mfma_scale_f32_32x32x64_f8f6f4(
                aF[s][1], bF1, acc[1][1], 0, 0, 0, 0x7F7F7F7F, 0, 0x7F7F7F7F);
        }

        // all waves done reading Bs[t&1] -> safe to re-stage it
        asm volatile("" ::: "memory");
        __builtin_amdgcn_s_barrier();
        asm volatile("" ::: "memory");
        if (t < 6) STAGE_B(t & 1, t + 2)

        // ---- per-tile epilogue: runs while B(t+1)/B(t+2) are in flight ----
        // nats/elem = ln2*max(y,0) + ln(1+2^-|y|);  ln(1+e) ~= e - e^2/2
#pragma unroll
        for (int mf = 0; mf < 2; ++mf)
#pragma unroll
            for (int nf = 0; nf < 2; ++nf)
#pragma unroll
                for (int q = 0; q < 16; ++q) {
                    float y = acc[mf][nf][q];
                    r1 += fmaxf(y, 0.f);
                    float e = __builtin_amdgcn_exp2f(-fabsf(y));
                    r2 += e;
                    r2b = fmaf(e, e, r2b);
                }

        // diagonal correction: only on the 2 tiles whose col-range meets rows
        if (diagblk && (t >> 1) == dtile) {
#pragma unroll
            for (int mf = 0; mf < 2; ++mf)
#pragma unroll
                for (int nf = 0; nf < 2; ++nf)
#pragma unroll
                    for (int q = 0; q < 16; ++q) {
                        int i_loc = wm * 64 + mf * 32 + (q & 3) + 8 * (q >> 2) + 4 * h;
                        int jg    = ((t & 1) << 7) + wn * 64 + nf * 32 + l31;
                        if (i_loc == jg) {
                            float y  = acc[mf][nf][q];
                            float u  = -(y + 2.f * b2);
                            float ey = __builtin_amdgcn_exp2f(-fabsf(y));
                            float eu = __builtin_amdgcn_exp2f(-fabsf(u));
                            float off = LN2 * fmaxf(y, 0.f) + ey - 0.5f * ey * ey;
                            float dg  = LN2 * fmaxf(u, 0.f) + eu - 0.5f * eu * eu;
                            ld += dg - off;
                        }
                    }
        }

        if (t < 6) {
            asm volatile("s_waitcnt vmcnt(4)" ::: "memory");  // B(t+1) landed
            __builtin_amdgcn_s_barrier();
            asm volatile("" ::: "memory");
        } else if (t == 6) {
            asm volatile("s_waitcnt vmcnt(0)" ::: "memory");  // B7 landed
            __builtin_amdgcn_s_barrier();
            asm volatile("" ::: "memory");
        }
    }

    float v = fmaf(LN2, r1, r2) - 0.5f * r2b + ld;   // nats

    // wave reduce then block reduce
#pragma unroll
    for (int off = 32; off; off >>= 1)
        v += __shfl_down(v, off);
    if (lane == 0) wsum[wid] = v;
    __syncthreads();
    if (tid == 0) {
        float t = 0.f;
#pragma unroll
        for (int w = 0; w < 8; ++w) t += wsum[w];
        atomicAdd(out, t * (1.0f / ((float)Nn * (float)Nn)));
    }
#undef STAGE_B
}

extern "C" void kernel_launch(void* const* d_in, const int* in_sizes, int n_in,
                              void* d_out, int out_size, void* d_ws, size_t ws_size,
                              hipStream_t stream) {
    const float* za   = (const float*)d_in[0];
    const float* zb   = (const float*)d_in[1];
    const float* bias = (const float*)d_in[2];

    unsigned char* wa = (unsigned char*)d_ws;
    unsigned char* wb = wa + (size_t)Nn * Dd;

    // zero the output accumulator (harness does not re-poison between replays)
    hipMemsetAsync(d_out, 0, sizeof(float), stream);

    // fp32 -> fp8 pre-pass (A pre-scaled by log2e)
    cvt_kernel<<<dim3(Nn * Dd / 2048), 256, 0, stream>>>(
        (const float4*)za, (const float4*)zb, (int2*)wa, (int2*)wb);

    // fused GEMM + loss: 64 M-tiles x 16 N-supertiles = 1024 blocks
    siglip_kernel<<<dim3(1024), 512, 0, stream>>>(wa, wb, bias, (float*)d_out);
}

// Round 9
// 296.233 us; speedup vs baseline: 2.3340x; 2.3340x over previous
//
#include <hip/hip_runtime.h>
#include <hip/hip_bf16.h>

#define Nn 16384
#define Dd 256
#define L2E 1.4426950408889634f
#define LN2 0.6931471805599453f

typedef __attribute__((ext_vector_type(8))) int int8v;
typedef __attribute__((ext_vector_type(16))) float f32x16;

__device__ inline void gload_lds16(const void* g, void* l) {
    __builtin_amdgcn_global_load_lds(
        (const __attribute__((address_space(1))) void*)g,
        (__attribute__((address_space(3))) void*)l, 16, 0, 0);
}

// fp32 -> fp8 e4m3 (HW RNE). A pre-scaled by log2e: epilogue softplus works in
// exp2/log2 domain with no per-element muls.
__global__ __launch_bounds__(256) void cvt_kernel(
        const float4* __restrict__ a, const float4* __restrict__ b,
        int2* __restrict__ oa, int2* __restrict__ ob) {
    int i = blockIdx.x * 256 + threadIdx.x;
    float4 a0 = a[2 * i], a1 = a[2 * i + 1];
    float4 b0 = b[2 * i], b1 = b[2 * i + 1];
    int alo = __builtin_amdgcn_cvt_pk_fp8_f32(a0.x * L2E, a0.y * L2E, 0, false);
    alo     = __builtin_amdgcn_cvt_pk_fp8_f32(a0.z * L2E, a0.w * L2E, alo, true);
    int ahi = __builtin_amdgcn_cvt_pk_fp8_f32(a1.x * L2E, a1.y * L2E, 0, false);
    ahi     = __builtin_amdgcn_cvt_pk_fp8_f32(a1.z * L2E, a1.w * L2E, ahi, true);
    int blo = __builtin_amdgcn_cvt_pk_fp8_f32(b0.x, b0.y, 0, false);
    blo     = __builtin_amdgcn_cvt_pk_fp8_f32(b0.z, b0.w, blo, true);
    int bhi = __builtin_amdgcn_cvt_pk_fp8_f32(b1.x, b1.y, 0, false);
    bhi     = __builtin_amdgcn_cvt_pk_fp8_f32(b1.z, b1.w, bhi, true);
    oa[i] = make_int2(alo, ahi);
    ob[i] = make_int2(blo, bhi);
}

// 2x ds_read_b128 of one lane's 32 contiguous K-bytes from a [rows][256B]
// full-K LDS tile, XOR-deswizzled (16 chunks/row, chunk ^= row&15).
// This layout measured ZERO bank conflicts (R8).
__device__ inline int8v read_frag256(const unsigned char* base, int rr, int cb) {
    int x = rr & 15;
    int4 lo = *(const int4*)&base[rr * 256 + ((cb ^ x) * 16)];
    int4 hi = *(const int4*)&base[rr * 256 + (((cb + 1) ^ x) * 16)];
    int8v r;
    r[0] = lo.x; r[1] = lo.y; r[2] = lo.z; r[3] = lo.w;
    r[4] = hi.x; r[5] = hi.y; r[6] = hi.z; r[7] = hi.w;
    return r;
}

// Fused MX-fp8 GEMM (sim' = log2e * za.zb^T, unit e8m0 scales) + siglip loss.
// Persistent-A pipelined-B: block = 256 M-rows x 1024 N-cols (8 tiles of 128).
// A[256][256B] staged once (64KB LDS), read from LDS per tile (transient
// frags — R8's 64-reg aF hoist was the spill driver, removed). B double-
// buffered [2][128][256B] (64KB), 2-tiles-ahead prefetch, counted vmcnt(4)
// only. Per-tile loss epilogue between stage-issue and wait hides HBM
// latency. 512 thr = 8 waves (4Mx2N), wave tile 64x64 -> acc[2][2] f32x16.
// t-loop unroll 1 to keep acc liveness single (R8's unroll-2 doubled it).
__global__ __launch_bounds__(512, 2) void siglip_kernel(
        const unsigned char* __restrict__ ga,   // za*log2e fp8 [16384][256]
        const unsigned char* __restrict__ gb,   // zb fp8 [16384][256]
        const float* __restrict__ bp,           // bias scalar
        float* __restrict__ out) {
    __shared__ unsigned char As[256 * 256];      // 64 KB
    __shared__ unsigned char Bs[2][128 * 256];   // 64 KB
    __shared__ float wsum[8];

    const int tid  = threadIdx.x;
    const int lane = tid & 63;
    const int wid  = tid >> 6;
    const int wm   = wid >> 1;     // 0..3 -> 64-row slice of the 256-row tile
    const int wn   = wid & 1;      // 0..1 -> 64-col slice of the 128-col tile
    const int l31  = lane & 31;
    const int h    = lane >> 5;

    // XCD-chunked bijective swizzle (grid 1024 = 8 XCD x 128); consecutive
    // nid share the A panel (same by) and sweep B -> per-XCD L2 locality.
    const int bid = blockIdx.x;
    const int nid = (bid & 7) * 128 + (bid >> 3);
    const int by  = nid >> 4;      // 0..63  M-tile (256 rows)
    const int bxs = nid & 15;      // 0..15  N-supertile (1024 cols)
    const size_t rowA0 = (size_t)by * 256;
    const int    rB0   = bxs * 1024;

    const float b2 = bp[0] * L2E;

    // ---- stage A once; source chunk pre-swizzled ((c&15)^(row&15)) so
    // read_frag256's XOR'd reads deswizzle correctly ----
#pragma unroll
    for (int p = 0; p < 8; ++p) {
        int c = p * 512 + tid; int row = c >> 4;
        int scl = (c & 15) ^ (row & 15);
        gload_lds16(&ga[(rowA0 + row) * Dd + scl * 16], &As[c * 16]);
    }

#define STAGE_B(BUF, T)                                                       \
    {                                                                         \
        _Pragma("unroll")                                                     \
        for (int p = 0; p < 4; ++p) {                                         \
            int c = p * 512 + tid; int row = c >> 4;                          \
            int scl = (c & 15) ^ (row & 15);                                  \
            gload_lds16(&gb[(size_t)(rB0 + (T) * 128 + row) * Dd + scl * 16], \
                        &Bs[BUF][c * 16]);                                    \
        }                                                                     \
    }

    STAGE_B(0, 0)
    STAGE_B(1, 1)

    // A(8) + B0(4) + B1(4) outstanding; wait until <=4 -> A and B0 landed.
    asm volatile("s_waitcnt vmcnt(4)" ::: "memory");
    __builtin_amdgcn_s_barrier();
    asm volatile("" ::: "memory");

    float r1 = 0.f, r2 = 0.f, r2b = 0.f, ld = 0.f;
    const int diagblk = (bxs == (by >> 2));
    const int dtile   = (by & 3);

#pragma unroll 1
    for (int t = 0; t < 8; ++t) {
        const unsigned char* Bb = Bs[t & 1];

        f32x16 acc[2][2];
#pragma unroll
        for (int mf = 0; mf < 2; ++mf)
#pragma unroll
            for (int nf = 0; nf < 2; ++nf)
#pragma unroll
                for (int q = 0; q < 16; ++q) acc[mf][nf][q] = -b2;

#pragma unroll
        for (int s = 0; s < 4; ++s) {
            int cb = s * 4 + h * 2;
            int8v aF0 = read_frag256(As, wm * 64 + l31, cb);
            int8v aF1 = read_frag256(As, wm * 64 + 32 + l31, cb);
            int8v bF0 = read_frag256(Bb, wn * 64 + l31, cb);
            int8v bF1 = read_frag256(Bb, wn * 64 + 32 + l31, cb);
            acc[0][0] = __builtin_amdgcn_mfma_scale_f32_32x32x64_f8f6f4(
                aF0, bF0, acc[0][0], 0, 0, 0, 0x7F7F7F7F, 0, 0x7F7F7F7F);
            acc[0][1] = __builtin_amdgcn_mfma_scale_f32_32x32x64_f8f6f4(
                aF0, bF1, acc[0][1], 0, 0, 0, 0x7F7F7F7F, 0, 0x7F7F7F7F);
            acc[1][0] = __builtin_amdgcn_mfma_scale_f32_32x32x64_f8f6f4(
                aF1, bF0, acc[1][0], 0, 0, 0, 0x7F7F7F7F, 0, 0x7F7F7F7F);
            acc[1][1] = __builtin_amdgcn_mfma_scale_f32_32x32x64_f8f6f4(
                aF1, bF1, acc[1][1], 0, 0, 0, 0x7F7F7F7F, 0, 0x7F7F7F7F);
        }

        // all waves done reading Bs[t&1] -> safe to re-stage it
        asm volatile("" ::: "memory");
        __builtin_amdgcn_s_barrier();
        asm volatile("" ::: "memory");
        if (t < 6) STAGE_B(t & 1, t + 2)

        // ---- per-tile epilogue: runs while B(t+1)/B(t+2) are in flight ----
        // nats/elem = ln2*max(y,0) + ln(1+2^-|y|);  ln(1+e) ~= e - e^2/2
#pragma unroll
        for (int mf = 0; mf < 2; ++mf)
#pragma unroll
            for (int nf = 0; nf < 2; ++nf)
#pragma unroll
                for (int q = 0; q < 16; ++q) {
                    float y = acc[mf][nf][q];
                    r1 += fmaxf(y, 0.f);
                    float e = __builtin_amdgcn_exp2f(-fabsf(y));
                    r2 += e;
                    r2b = fmaf(e, e, r2b);
                }

        // diagonal correction: only on tiles whose col-range meets row-range
        if (diagblk && (t >> 1) == dtile) {
#pragma unroll
            for (int mf = 0; mf < 2; ++mf)
#pragma unroll
                for (int nf = 0; nf < 2; ++nf)
#pragma unroll
                    for (int q = 0; q < 16; ++q) {
                        int i_loc = wm * 64 + mf * 32 + (q & 3) + 8 * (q >> 2) + 4 * h;
                        int jg    = ((t & 1) << 7) + wn * 64 + nf * 32 + l31;
                        if (i_loc == jg) {
                            float y  = acc[mf][nf][q];
                            float u  = -(y + 2.f * b2);
                            float ey = __builtin_amdgcn_exp2f(-fabsf(y));
                            float eu = __builtin_amdgcn_exp2f(-fabsf(u));
                            float off = LN2 * fmaxf(y, 0.f) + ey - 0.5f * ey * ey;
                            float dg  = LN2 * fmaxf(u, 0.f) + eu - 0.5f * eu * eu;
                            ld += dg - off;
                        }
                    }
        }

        if (t < 6) {
            asm volatile("s_waitcnt vmcnt(4)" ::: "memory");  // B(t+1) landed
            __builtin_amdgcn_s_barrier();
            asm volatile("" ::: "memory");
        } else if (t == 6) {
            asm volatile("s_waitcnt vmcnt(0)" ::: "memory");  // B7 landed
            __builtin_amdgcn_s_barrier();
            asm volatile("" ::: "memory");
        }
    }

    float v = fmaf(LN2, r1, r2) - 0.5f * r2b + ld;   // nats

    // wave reduce then block reduce
#pragma unroll
    for (int off = 32; off; off >>= 1)
        v += __shfl_down(v, off);
    if (lane == 0) wsum[wid] = v;
    __syncthreads();
    if (tid == 0) {
        float t = 0.f;
#pragma unroll
        for (int w = 0; w < 8; ++w) t += wsum[w];
        atomicAdd(out, t * (1.0f / ((float)Nn * (float)Nn)));
    }
#undef STAGE_B
}

extern "C" void kernel_launch(void* const* d_in, const int* in_sizes, int n_in,
                              void* d_out, int out_size, void* d_ws, size_t ws_size,
                              hipStream_t stream) {
    const float* za   = (const float*)d_in[0];
    const float* zb   = (const float*)d_in[1];
    const float* bias = (const float*)d_in[2];

    unsigned char* wa = (unsigned char*)d_ws;
    unsigned char* wb = wa + (size_t)Nn * Dd;

    // zero the output accumulator (harness does not re-poison between replays)
    hipMemsetAsync(d_out, 0, sizeof(float), stream);

    // fp32 -> fp8 pre-pass (A pre-scaled by log2e)
    cvt_kernel<<<dim3(Nn * Dd / 2048), 256, 0, stream>>>(
        (const float4*)za, (const float4*)zb, (int2*)wa, (int2*)wb);

    // fused GEMM + loss: 64 M-tiles x 16 N-supertiles = 1024 blocks
    siglip_kernel<<<dim3(1024), 512, 0, stream>>>(wa, wb, bias, (float*)d_out);
}

// Round 10
// 147.638 us; speedup vs baseline: 4.6832x; 2.0065x over previous
//
#include <hip/hip_runtime.h>
#include <hip/hip_bf16.h>

#define Nn 16384
#define Dd 256
#define L2E 1.4426950408889634f
#define LN2 0.6931471805599453f

typedef __attribute__((ext_vector_type(8))) int int8v;
typedef __attribute__((ext_vector_type(16))) float f32x16;

__device__ inline void gload_lds16(const void* g, void* l) {
    __builtin_amdgcn_global_load_lds(
        (const __attribute__((address_space(1))) void*)g,
        (__attribute__((address_space(3))) void*)l, 16, 0, 0);
}

// fp32 -> fp8 e4m3 (HW RNE). A pre-scaled by log2e: epilogue softplus works in
// exp2/log2 domain with no per-element muls.
__global__ __launch_bounds__(256) void cvt_kernel(
        const float4* __restrict__ a, const float4* __restrict__ b,
        int2* __restrict__ oa, int2* __restrict__ ob) {
    int i = blockIdx.x * 256 + threadIdx.x;
    float4 a0 = a[2 * i], a1 = a[2 * i + 1];
    float4 b0 = b[2 * i], b1 = b[2 * i + 1];
    int alo = __builtin_amdgcn_cvt_pk_fp8_f32(a0.x * L2E, a0.y * L2E, 0, false);
    alo     = __builtin_amdgcn_cvt_pk_fp8_f32(a0.z * L2E, a0.w * L2E, alo, true);
    int ahi = __builtin_amdgcn_cvt_pk_fp8_f32(a1.x * L2E, a1.y * L2E, 0, false);
    ahi     = __builtin_amdgcn_cvt_pk_fp8_f32(a1.z * L2E, a1.w * L2E, ahi, true);
    int blo = __builtin_amdgcn_cvt_pk_fp8_f32(b0.x, b0.y, 0, false);
    blo     = __builtin_amdgcn_cvt_pk_fp8_f32(b0.z, b0.w, blo, true);
    int bhi = __builtin_amdgcn_cvt_pk_fp8_f32(b1.x, b1.y, 0, false);
    bhi     = __builtin_amdgcn_cvt_pk_fp8_f32(b1.z, b1.w, bhi, true);
    oa[i] = make_int2(alo, ahi);
    ob[i] = make_int2(blo, bhi);
}

// 2x ds_read_b128 of one lane's 32 contiguous K-bytes from a [rows][256B]
// full-K LDS tile, XOR-deswizzled (16 chunks/row, chunk ^= row&15).
// This layout measured ZERO bank conflicts (R8/R9).
__device__ inline int8v read_frag256(const unsigned char* base, int rr, int cb) {
    int x = rr & 15;
    int4 lo = *(const int4*)&base[rr * 256 + ((cb ^ x) * 16)];
    int4 hi = *(const int4*)&base[rr * 256 + (((cb + 1) ^ x) * 16)];
    int8v r;
    r[0] = lo.x; r[1] = lo.y; r[2] = lo.z; r[3] = lo.w;
    r[4] = hi.x; r[5] = hi.y; r[6] = hi.z; r[7] = hi.w;
    return r;
}

// Fused MX-fp8 GEMM (sim' = log2e * za.zb^T, unit e8m0 scales) + siglip loss.
// STRAIGHT-LINE block (no output-tile loop — R8/R9 showed loops make the
// compiler keep 2 acc generations -> 256 unified regs -> spill):
// tile 256(M)x128(N), FULL K=256 staged in one shot (A 64KB + B 32KB LDS,
// conflict-free 256B-row XOR-16 layout), one vmcnt(0)+barrier, 16 MFMAs,
// register-only epilogue. 512 thr = 8 waves (4M x 2N), wave tile 64x64 ->
// acc[2][2] f32x16 (64 regs, R6-proven shape: ~116 VGPR + 64 AGPR, no spill).
__global__ __launch_bounds__(512, 2) void siglip_kernel(
        const unsigned char* __restrict__ ga,   // za*log2e fp8 [16384][256]
        const unsigned char* __restrict__ gb,   // zb fp8 [16384][256]
        const float* __restrict__ bp,           // bias scalar
        float* __restrict__ out) {
    __shared__ unsigned char As[256 * 256];   // 64 KB, full-K A tile
    __shared__ unsigned char Bs[128 * 256];   // 32 KB, full-K B tile
    __shared__ float wsum[8];

    const int tid  = threadIdx.x;
    const int lane = tid & 63;
    const int wid  = tid >> 6;
    const int wm   = wid >> 1;     // 0..3 -> 64-row slice of the 256-row tile
    const int wn   = wid & 1;      // 0..1 -> 64-col slice of the 128-col tile
    const int l31  = lane & 31;
    const int h    = lane >> 5;

    // XCD-chunked swizzle + 8x8 supertile (grid 8192 = 8 XCD x 1024).
    const int bid = blockIdx.x;
    const int nid = (bid & 7) * 1024 + (bid >> 3);
    const int sc  = nid >> 6, sl = nid & 63;
    const int by  = (sc & 7) * 8 + (sl >> 3);    // 0..63  (M/256)
    const int bx  = (sc >> 3) * 8 + (sl & 7);    // 0..127 (N/128)
    const size_t rowA0 = (size_t)by * 256;
    const size_t rowB0 = (size_t)bx * 128;

    const float b2 = bp[0] * L2E;

    // ---- stage the whole problem slice ONCE: 12 loads/thread ----
    // source chunk pre-swizzled ((c&15)^(row&15)) so read_frag256's XOR'd
    // ds_read_b128 deswizzles correctly (bank-conflict-free, R8-proven).
#pragma unroll
    for (int p = 0; p < 8; ++p) {
        int c = p * 512 + tid; int row = c >> 4;
        int scl = (c & 15) ^ (row & 15);
        gload_lds16(&ga[(rowA0 + row) * Dd + scl * 16], &As[c * 16]);
    }
#pragma unroll
    for (int p = 0; p < 4; ++p) {
        int c = p * 512 + tid; int row = c >> 4;
        int scl = (c & 15) ^ (row & 15);
        gload_lds16(&gb[(rowB0 + row) * Dd + scl * 16], &Bs[c * 16]);
    }

    // bias folded into MFMA C operand: acc ends as y = s' - b2
    f32x16 acc[2][2];
#pragma unroll
    for (int mf = 0; mf < 2; ++mf)
#pragma unroll
        for (int nf = 0; nf < 2; ++nf)
#pragma unroll
            for (int q = 0; q < 16; ++q) acc[mf][nf][q] = -b2;

    asm volatile("s_waitcnt vmcnt(0)" ::: "memory");
    __builtin_amdgcn_s_barrier();
    asm volatile("" ::: "memory");

    // ---- K = 256 in 4 s-steps of 64B, straight-line, 16 MFMAs ----
#pragma unroll
    for (int s = 0; s < 4; ++s) {
        int cb = s * 4 + h * 2;
        int8v aF0 = read_frag256(As, wm * 64 + l31, cb);
        int8v aF1 = read_frag256(As, wm * 64 + 32 + l31, cb);
        int8v bF0 = read_frag256(Bs, wn * 64 + l31, cb);
        int8v bF1 = read_frag256(Bs, wn * 64 + 32 + l31, cb);
        acc[0][0] = __builtin_amdgcn_mfma_scale_f32_32x32x64_f8f6f4(
            aF0, bF0, acc[0][0], 0, 0, 0, 0x7F7F7F7F, 0, 0x7F7F7F7F);
        acc[0][1] = __builtin_amdgcn_mfma_scale_f32_32x32x64_f8f6f4(
            aF0, bF1, acc[0][1], 0, 0, 0, 0x7F7F7F7F, 0, 0x7F7F7F7F);
        acc[1][0] = __builtin_amdgcn_mfma_scale_f32_32x32x64_f8f6f4(
            aF1, bF0, acc[1][0], 0, 0, 0, 0x7F7F7F7F, 0, 0x7F7F7F7F);
        acc[1][1] = __builtin_amdgcn_mfma_scale_f32_32x32x64_f8f6f4(
            aF1, bF1, acc[1][1], 0, 0, 0, 0x7F7F7F7F, 0, 0x7F7F7F7F);
    }
    // no trailing barrier: waves desync into the VALU/trans epilogue.

    // ---- epilogue: nats/elem = ln2*max(y,0) + ln(1+2^-|y|) ~= ln2*r1 + e
    // (dropping e^2/2: mean bias ~ -0.007, 18x under the 0.128 budget) ----
    float r1 = 0.f, r2 = 0.f, ld = 0.f;
#pragma unroll
    for (int mf = 0; mf < 2; ++mf)
#pragma unroll
        for (int nf = 0; nf < 2; ++nf)
#pragma unroll
            for (int q = 0; q < 16; ++q) {
                float y = acc[mf][nf][q];
                r1 += fmaxf(y, 0.f);
                r2 += __builtin_amdgcn_exp2f(-fabsf(y));
            }

    // Diagonal correction where this block's row-range meets its col-range.
    if ((bx >> 1) == by) {
#pragma unroll
        for (int mf = 0; mf < 2; ++mf)
#pragma unroll
            for (int nf = 0; nf < 2; ++nf)
#pragma unroll
                for (int q = 0; q < 16; ++q) {
                    int i_loc = wm * 64 + mf * 32 + (q & 3) + 8 * (q >> 2) + 4 * h;
                    int j_loc = (bx & 1) * 128 + wn * 64 + nf * 32 + l31;
                    if (i_loc == j_loc) {
                        float y  = acc[mf][nf][q];
                        float u  = -(y + 2.f * b2);
                        float ey = __builtin_amdgcn_exp2f(-fabsf(y));
                        float eu = __builtin_amdgcn_exp2f(-fabsf(u));
                        float off = LN2 * fmaxf(y, 0.f) + ey;
                        float dg  = LN2 * fmaxf(u, 0.f) + eu;
                        ld += dg - off;
                    }
                }
    }

    float v = fmaf(LN2, r1, r2) + ld;   // nats

    // wave reduce then block reduce
#pragma unroll
    for (int off = 32; off; off >>= 1)
        v += __shfl_down(v, off);
    if (lane == 0) wsum[wid] = v;
    __syncthreads();
    if (tid == 0) {
        float t = 0.f;
#pragma unroll
        for (int w = 0; w < 8; ++w) t += wsum[w];
        atomicAdd(out, t * (1.0f / ((float)Nn * (float)Nn)));
    }
}

extern "C" void kernel_launch(void* const* d_in, const int* in_sizes, int n_in,
                              void* d_out, int out_size, void* d_ws, size_t ws_size,
                              hipStream_t stream) {
    const float* za   = (const float*)d_in[0];
    const float* zb   = (const float*)d_in[1];
    const float* bias = (const float*)d_in[2];

    unsigned char* wa = (unsigned char*)d_ws;
    unsigned char* wb = wa + (size_t)Nn * Dd;

    // zero the output accumulator (harness does not re-poison between replays)
    hipMemsetAsync(d_out, 0, sizeof(float), stream);

    // fp32 -> fp8 pre-pass (A pre-scaled by log2e)
    cvt_kernel<<<dim3(Nn * Dd / 2048), 256, 0, stream>>>(
        (const float4*)za, (const float4*)zb, (int2*)wa, (int2*)wb);

    // fused GEMM + loss: grid 64 x 128 = 8192 blocks
    siglip_kernel<<<dim3(8192), 512, 0, stream>>>(wa, wb, bias, (float*)d_out);
}